// Round 19
// baseline (271.161 us; speedup 1.0000x reference)
//
#include <hip/hip_runtime.h>

// Problem constants (B=4, C=512, G=32, H=W=64)
#define B_   4
#define C_   512
#define G_   32
#define CPG  16          // channels per group
#define N_   4096        // H*W

typedef unsigned short u16;
typedef __attribute__((ext_vector_type(4))) float f32x4;
typedef __attribute__((ext_vector_type(8))) short s16x8;
typedef __attribute__((ext_vector_type(8))) u16   u16x8;
typedef __attribute__((ext_vector_type(4))) u16   u16x4;

__device__ __forceinline__ u16 f2bf(float f) {
    union { float f; unsigned u; } x; x.f = f;
    unsigned r = x.u + 0x7fffu + ((x.u >> 16) & 1u);   // RNE
    return (u16)(r >> 16);
}

// ---------------------------------------------------------------------------
// prep: blocks 0..1023 = GN partial sums (8 slices per (b,g));
//       blocks 1024..1279 = weight bf16 conversion. One dispatch.
// ---------------------------------------------------------------------------
__global__ __launch_bounds__(256)
void prep_kernel(const float* __restrict__ x, float2* __restrict__ gpart,
                 const float* __restrict__ wq, const float* __restrict__ wk,
                 const float* __restrict__ wv, const float* __restrict__ wo,
                 u16* __restrict__ wqb, u16* __restrict__ wkb,
                 u16* __restrict__ wvb, u16* __restrict__ wob)
{
    int blk = blockIdx.x;
    int t = threadIdx.x;
    if (blk < 1024) {
        int bg = blk >> 3, s = blk & 7;  // group 0..127, slice 0..7
        const float* base = x + (size_t)bg * CPG * N_ + s * 8192;
        float sm = 0.f, ss = 0.f;
        #pragma unroll
        for (int i = 0; i < 8192; i += 1024) {
            float4 v = *reinterpret_cast<const float4*>(base + i + t * 4);
            sm += v.x + v.y + v.z + v.w;
            ss += v.x * v.x + v.y * v.y + v.z * v.z + v.w * v.w;
        }
        __shared__ float rs[256], rss[256];
        rs[t] = sm; rss[t] = ss;
        __syncthreads();
        for (int off = 128; off > 0; off >>= 1) {
            if (t < off) { rs[t] += rs[t + off]; rss[t] += rss[t + off]; }
            __syncthreads();
        }
        if (t == 0) gpart[blk] = make_float2(rs[0], rss[0]);
    } else {
        int idx = ((blk - 1024) * 256 + t) * 4;
        {
            float4 a = *reinterpret_cast<const float4*>(wq + idx);
            u16x4 r = { f2bf(a.x), f2bf(a.y), f2bf(a.z), f2bf(a.w) };
            *reinterpret_cast<u16x4*>(wqb + idx) = r;
        }
        {
            float4 a = *reinterpret_cast<const float4*>(wk + idx);
            u16x4 r = { f2bf(a.x), f2bf(a.y), f2bf(a.z), f2bf(a.w) };
            *reinterpret_cast<u16x4*>(wkb + idx) = r;
        }
        {
            float4 a = *reinterpret_cast<const float4*>(wv + idx);
            u16x4 r = { f2bf(a.x), f2bf(a.y), f2bf(a.z), f2bf(a.w) };
            *reinterpret_cast<u16x4*>(wvb + idx) = r;
        }
        {
            float4 a = *reinterpret_cast<const float4*>(wo + idx);
            u16x4 r = { f2bf(a.x), f2bf(a.y), f2bf(a.z), f2bf(a.w) };
            *reinterpret_cast<u16x4*>(wob + idx) = r;
        }
    }
}

// ---------------------------------------------------------------------------
// GN-apply + transpose + bf16: x[b][c][n] f32 -> nx_t[b][n][c] bf16.
// Per-block inline stats from gpart (fixed-order sums -> deterministic;
// replaces the 1-block gn_combine serialization bubble).
// ---------------------------------------------------------------------------
__global__ __launch_bounds__(256)
void nxt_kernel(const float* __restrict__ x, const float2* __restrict__ gpart,
                const float* __restrict__ gamma, const float* __restrict__ beta,
                u16* __restrict__ nx_t)
{
    int b  = blockIdx.z;
    int n0 = blockIdx.x * 64, c0 = blockIdx.y * 64;
    const float* xb = x + ((size_t)b * C_ + c0) * N_ + n0;
    u16* ob = nx_t + ((size_t)b * N_ + n0) * C_ + c0;
    int t = threadIdx.x;
    int tx = t & 15, ty = t >> 4;

    __shared__ float scale_s[64], shift_s[64];
    if (t < 64) {
        int c = c0 + t;
        int bg = b * G_ + (c >> 4);
        float sm = 0.f, ss = 0.f;
        #pragma unroll
        for (int s = 0; s < 8; ++s) {
            float2 p2 = gpart[bg * 8 + s];
            sm += p2.x; ss += p2.y;
        }
        const float inv_n = 1.f / 65536.f;
        float mean = sm * inv_n;
        float var  = ss * inv_n - mean * mean;
        float rstd = rsqrtf(var + 1e-6f);
        float sc = gamma[c] * rstd;
        scale_s[t] = sc;
        shift_s[t] = beta[c] - mean * sc;
    }
    __syncthreads();

    __shared__ float tile[64][65];
    #pragma unroll
    for (int r = 0; r < 4; ++r) {
        int c = ty * 4 + r;
        float sc = scale_s[c];
        float sh = shift_s[c];
        float4 v = *reinterpret_cast<const float4*>(xb + (size_t)c * N_ + tx * 4);
        tile[c][tx * 4 + 0] = v.x * sc + sh;
        tile[c][tx * 4 + 1] = v.y * sc + sh;
        tile[c][tx * 4 + 2] = v.z * sc + sh;
        tile[c][tx * 4 + 3] = v.w * sc + sh;
    }
    __syncthreads();
    int nn = t >> 2, cc0 = (t & 3) * 16;
    u16x8 o0, o1;
    #pragma unroll
    for (int j = 0; j < 8; ++j) o0[j] = f2bf(tile[cc0 + j][nn]);
    #pragma unroll
    for (int j = 0; j < 8; ++j) o1[j] = f2bf(tile[cc0 + 8 + j][nn]);
    *reinterpret_cast<u16x8*>(ob + (size_t)nn * C_ + cc0)     = o0;
    *reinterpret_cast<u16x8*>(ob + (size_t)nn * C_ + cc0 + 8) = o1;
}

// ---------------------------------------------------------------------------
// TN bf16 MFMA GEMM: D[i][j] = sum_k A[i][k] * B[j][k]
// BM x BN tile, BK=64, 4 waves (2x2), 16x16x32 MFMA, global_load_lds staging.
// Granule XOR-swizzle (both-sides, proven r5: bank conflicts = 0).
// EPI: 0 = bf16 out + bias[j]; 1 = bf16 out + bias[i];
//      2 = bf16 exp(acc*scl) out + BLOCK-REDUCED row sums -> psum;
//      3 = f32 out: acc * colsc[j] + bias[i] + resid[i][j]; 4 = bf16 plain.
// ---------------------------------------------------------------------------
template<int BM, int BN, int EPI>
__device__ __forceinline__
void gemm_dev(int i0, int j0,
              const u16* __restrict__ A, const u16* __restrict__ B,
              void* __restrict__ Dp, const float* __restrict__ bias,
              const float* __restrict__ resid,
              int Nn, int K, int lda, int ldb, float scl,
              float* __restrict__ psum, const float* __restrict__ colsc)
{
    constexpr int WM = BM / 2, WN = BN / 2;   // wave tile
    constexpr int MI = WM / 16, NI = WN / 16; // fragments per wave

    __shared__ u16 As[BM * 64];
    __shared__ u16 Bs[BN * 64];

    const int t  = threadIdx.x;
    const int l  = t & 63;
    const int w  = t >> 6;          // wave 0..3
    const int wr = w >> 1;          // i-half
    const int wc = w & 1;           // j-half

    const int srow = l >> 3;                    // row within 8-row segment
    const int sgr  = ((l & 7) ^ (l >> 3)) * 8;  // swizzled global k-offset (u16)

    const int fr = l & 15;          // fragment row
    const int q  = l >> 4;          // fragment k-quarter

    f32x4 acc[MI][NI];
    #pragma unroll
    for (int a = 0; a < MI; ++a)
        #pragma unroll
        for (int b2 = 0; b2 < NI; ++b2) acc[a][b2] = 0.f;

    for (int k0 = 0; k0 < K; k0 += 64) {
        #pragma unroll
        for (int r = 0; r < BM / 32; ++r) {
            int s = r * 4 + w;      // 8-row segment
            const u16* ga = A + (size_t)(i0 + s * 8 + srow) * lda + (k0 + sgr);
            __builtin_amdgcn_global_load_lds(
                (const __attribute__((address_space(1))) void*)ga,
                (__attribute__((address_space(3))) void*)&As[s * 512], 16, 0, 0);
        }
        #pragma unroll
        for (int r = 0; r < BN / 32; ++r) {
            int s = r * 4 + w;
            const u16* gb = B + (size_t)(j0 + s * 8 + srow) * ldb + (k0 + sgr);
            __builtin_amdgcn_global_load_lds(
                (const __attribute__((address_space(1))) void*)gb,
                (__attribute__((address_space(3))) void*)&Bs[s * 512], 16, 0, 0);
        }
        __syncthreads();

        #pragma unroll
        for (int h = 0; h < 2; ++h) {
            s16x8 af[MI], bfr[NI];
            #pragma unroll
            for (int mi = 0; mi < MI; ++mi) {
                int r = wr * WM + mi * 16 + fr;
                int p = (h * 4 + q) ^ (r & 7);
                af[mi] = *reinterpret_cast<const s16x8*>(&As[r * 64 + p * 8]);
            }
            #pragma unroll
            for (int ni = 0; ni < NI; ++ni) {
                int r = wc * WN + ni * 16 + fr;
                int p = (h * 4 + q) ^ (r & 7);
                bfr[ni] = *reinterpret_cast<const s16x8*>(&Bs[r * 64 + p * 8]);
            }
            #pragma unroll
            for (int mi = 0; mi < MI; ++mi)
                #pragma unroll
                for (int ni = 0; ni < NI; ++ni)
                    acc[mi][ni] = __builtin_amdgcn_mfma_f32_16x16x32_bf16(
                        af[mi], bfr[ni], acc[mi][ni], 0, 0, 0);
        }
        __syncthreads();
    }

    const int orow = (l >> 4) * 4;
    const int ocol = l & 15;

    if constexpr (EPI == 2) {
        __shared__ float sstl[2][2][64];   // [wr][wc][row64]
        u16* D = (u16*)Dp;
        #pragma unroll
        for (int mi = 0; mi < MI; ++mi) {
            int ib = i0 + wr * WM + mi * 16 + orow;
            float pr[4] = {0.f, 0.f, 0.f, 0.f};
            #pragma unroll
            for (int ni = 0; ni < NI; ++ni) {
                int jb = j0 + wc * WN + ni * 16 + ocol;
                #pragma unroll
                for (int e = 0; e < 4; ++e) {
                    float ex = __expf(acc[mi][ni][e] * scl);
                    D[(size_t)(ib + e) * Nn + jb] = f2bf(ex);
                    pr[e] += ex;
                }
            }
            #pragma unroll
            for (int e = 0; e < 4; ++e) {
                pr[e] += __shfl_xor(pr[e], 1);
                pr[e] += __shfl_xor(pr[e], 2);
                pr[e] += __shfl_xor(pr[e], 4);
                pr[e] += __shfl_xor(pr[e], 8);
            }
            if ((l & 15) == 0) {
                #pragma unroll
                for (int e = 0; e < 4; ++e)
                    sstl[wr][wc][mi * 16 + (l >> 4) * 4 + e] = pr[e];
            }
        }
        __syncthreads();
        if (t < 128) {
            int wr2 = t >> 6, r = t & 63;
            psum[i0 + wr2 * 64 + r] = sstl[wr2][0][r] + sstl[wr2][1][r];
        }
    } else {
        #pragma unroll
        for (int mi = 0; mi < MI; ++mi) {
            #pragma unroll
            for (int ni = 0; ni < NI; ++ni) {
                int ib = i0 + wr * WM + mi * 16 + orow;
                int jb = j0 + wc * WN + ni * 16 + ocol;
                if constexpr (EPI == 0 || EPI == 1 || EPI == 4) {
                    u16* D = (u16*)Dp;
                    float bj = 0.f;
                    if constexpr (EPI == 0) bj = bias[jb];
                    #pragma unroll
                    for (int e = 0; e < 4; ++e) {
                        float vv = acc[mi][ni][e];
                        if constexpr (EPI == 0) vv += bj;
                        if constexpr (EPI == 1) vv += bias[ib + e];
                        D[(size_t)(ib + e) * Nn + jb] = f2bf(vv);
                    }
                } else {   // EPI == 3: colsc per output column + bias + resid
                    float* D = (float*)Dp;
                    float cs = colsc[jb];
                    #pragma unroll
                    for (int e = 0; e < 4; ++e)
                        D[(size_t)(ib + e) * Nn + jb] =
                            acc[mi][ni][e] * cs + bias[ib + e] + resid[(size_t)(ib + e) * Nn + jb];
                }
            }
        }
    }
}

// qkv: z 0..7 = q/k projections (EPI0, D[n][co]); z 8..11 = v (EPI1, D[co][n]).
// grid (32, 4, 12).
__global__ __launch_bounds__(256)
void qkv_gemm(const u16* __restrict__ nx_t, const u16* __restrict__ wqb,
              const u16* __restrict__ wkb, const u16* __restrict__ wvb,
              const float* __restrict__ bq, const float* __restrict__ bk,
              const float* __restrict__ bv, u16* __restrict__ q_t,
              u16* __restrict__ k_t, u16* __restrict__ vbuf)
{
    int z = blockIdx.z;
    if (z < 8) {
        int b = z & 3, isk = z >> 2;
        gemm_dev<128, 128, 0>(blockIdx.x * 128, blockIdx.y * 128,
                              nx_t + (size_t)b * N_ * C_, isk ? wkb : wqb,
                              (isk ? k_t : q_t) + (size_t)b * N_ * C_,
                              isk ? bk : bq, nullptr, C_, C_, C_, C_, 1.f,
                              nullptr, nullptr);
    } else {
        int b = z - 8;
        gemm_dev<128, 128, 1>(blockIdx.y * 128, blockIdx.x * 128,
                              wvb, nx_t + (size_t)b * N_ * C_,
                              vbuf + (size_t)b * C_ * N_,
                              bv, nullptr, N_, C_, C_, C_, 1.f, nullptr, nullptr);
    }
}

// scores: P_raw[b][i][j] = exp(S) bf16 + block-reduced row-sum partials.
// r13-proven 3-D grid (32,32,4).
__global__ __launch_bounds__(256)
void scores_gemm(const u16* __restrict__ q_t, const u16* __restrict__ k_t,
                 u16* __restrict__ S_bf, float* __restrict__ psum)
{
    int b = blockIdx.z;
    float* ps = psum + ((size_t)b * 32 + blockIdx.x) * N_;   // [b][jt][i]
    gemm_dev<128, 128, 2>(blockIdx.y * 128, blockIdx.x * 128,
                          q_t + (size_t)b * N_ * C_, k_t + (size_t)b * N_ * C_,
                          S_bf + (size_t)b * N_ * N_, nullptr, nullptr, N_, C_, C_, C_,
                          0.044194173824159216f, ps, nullptr);
}

// Combine psum[b][jt][i] over jt -> inv_l[b*N+i]. 2 MB, L2-resident.
// grid B*N/256 x 256.
__global__ __launch_bounds__(256)
void lsum_kernel(const float* __restrict__ psum, float* __restrict__ inv_l)
{
    int r = blockIdx.x * 256 + threadIdx.x;   // global row b*N+i
    int b = r >> 12, i = r & (N_ - 1);
    const float* p = psum + (size_t)b * 32 * N_ + i;
    float s = 0.f;
    #pragma unroll
    for (int jt = 0; jt < 32; ++jt) s += p[(size_t)jt * N_];
    inv_l[r] = 1.f / s;
}

// ---------------------------------------------------------------------------
// PV (unnormalized): attn_t[i][c] = sum_j P_raw[i][j] * v[c][j].
// r13-proven plain body. LDS staging, XOR swizzle, XCD-gather, BM=128 i,
// BN=64 c, BK=64. grid 1024 blocks.
// ---------------------------------------------------------------------------
__global__ __launch_bounds__(256)
void pv_part(const u16* __restrict__ S_bf, const u16* __restrict__ vbuf,
             u16* __restrict__ attn_t)
{
    int id  = blockIdx.x;          // 0..1023
    int xcd = id & 7, slot = id >> 3;
    int yz  = xcd * 16 + (slot >> 3);   // (i-tile, b) combo, 0..127
    int ct  = slot & 7;                 // c-tile 0..7
    int it  = yz & 31, b = yz >> 5;
    const u16* Pb = S_bf + (size_t)b * N_ * N_;
    const u16* Vb = vbuf + (size_t)b * C_ * N_;
    u16*       Ob = attn_t + (size_t)b * N_ * C_;

    const int i0 = it * 128, c0 = ct * 64;
    const int t = threadIdx.x, l = t & 63, w = t >> 6;
    const int wr = w >> 1, wc = w & 1;       // WM=64, WN=32, MI=4, NI=2
    const int srow = l >> 3;
    const int sgr  = ((l & 7) ^ (l >> 3)) * 8;
    const int fr = l & 15, q = l >> 4;

    __shared__ u16 As[128 * 64];
    __shared__ u16 Bs[64 * 64];

    f32x4 acc[4][2];
    #pragma unroll
    for (int a = 0; a < 4; ++a)
        #pragma unroll
        for (int b2 = 0; b2 < 2; ++b2) acc[a][b2] = 0.f;

    for (int k0 = 0; k0 < N_; k0 += 64) {
        #pragma unroll
        for (int r = 0; r < 4; ++r) {
            int s = r * 4 + w;
            const u16* ga = Pb + (size_t)(i0 + s * 8 + srow) * N_ + (k0 + sgr);
            __builtin_amdgcn_global_load_lds(
                (const __attribute__((address_space(1))) void*)ga,
                (__attribute__((address_space(3))) void*)&As[s * 512], 16, 0, 0);
        }
        #pragma unroll
        for (int r = 0; r < 2; ++r) {
            int s = r * 4 + w;
            const u16* gb = Vb + (size_t)(c0 + s * 8 + srow) * N_ + (k0 + sgr);
            __builtin_amdgcn_global_load_lds(
                (const __attribute__((address_space(1))) void*)gb,
                (__attribute__((address_space(3))) void*)&Bs[s * 512], 16, 0, 0);
        }
        __syncthreads();
        #pragma unroll
        for (int h = 0; h < 2; ++h) {
            s16x8 af[4], bfr[2];
            #pragma unroll
            for (int mi = 0; mi < 4; ++mi) {
                int r = wr * 64 + mi * 16 + fr;
                int p = (h * 4 + q) ^ (r & 7);
                af[mi] = *reinterpret_cast<const s16x8*>(&As[r * 64 + p * 8]);
            }
            #pragma unroll
            for (int ni = 0; ni < 2; ++ni) {
                int r = wc * 32 + ni * 16 + fr;
                int p = (h * 4 + q) ^ (r & 7);
                bfr[ni] = *reinterpret_cast<const s16x8*>(&Bs[r * 64 + p * 8]);
            }
            #pragma unroll
            for (int mi = 0; mi < 4; ++mi)
                #pragma unroll
                for (int ni = 0; ni < 2; ++ni)
                    acc[mi][ni] = __builtin_amdgcn_mfma_f32_16x16x32_bf16(
                        af[mi], bfr[ni], acc[mi][ni], 0, 0, 0);
        }
        __syncthreads();
    }

    const int orow = (l >> 4) * 4;
    const int ocol = l & 15;
    #pragma unroll
    for (int mi = 0; mi < 4; ++mi) {
        #pragma unroll
        for (int ni = 0; ni < 2; ++ni) {
            int ib = i0 + wr * 64 + mi * 16 + orow;
            int jb = c0 + wc * 32 + ni * 16 + ocol;
            #pragma unroll
            for (int e = 0; e < 4; ++e)
                Ob[(size_t)(ib + e) * C_ + jb] = f2bf(acc[mi][ni][e]);
        }
    }
}

// final: out[co][n] = x + bo[co] + inv_l[n] * sum_ci wo[co][ci]*attn_t[n][ci].
// grid (32,4,4)
__global__ __launch_bounds__(256)
void final_gemm(const u16* __restrict__ wob, const u16* __restrict__ attn_t,
                const float* __restrict__ bo, const float* __restrict__ x,
                const float* __restrict__ inv_l, float* __restrict__ outp)
{
    int b = blockIdx.z;
    gemm_dev<128, 128, 3>(blockIdx.y * 128, blockIdx.x * 128,
                          wob, attn_t + (size_t)b * N_ * C_, outp + (size_t)b * C_ * N_,
                          bo, x + (size_t)b * C_ * N_, N_, C_, C_, C_, 1.f,
                          nullptr, inv_l + (size_t)b * N_);
}

// ---------------------------------------------------------------------------
extern "C" void kernel_launch(void* const* d_in, const int* in_sizes, int n_in,
                              void* d_out, int out_size, void* d_ws, size_t ws_size,
                              hipStream_t stream)
{
    const float* x     = (const float*)d_in[0];
    const float* gamma = (const float*)d_in[1];
    const float* beta  = (const float*)d_in[2];
    const float* wq    = (const float*)d_in[3];
    const float* bq    = (const float*)d_in[4];
    const float* wk    = (const float*)d_in[5];
    const float* bk    = (const float*)d_in[6];
    const float* wv    = (const float*)d_in[7];
    const float* bv    = (const float*)d_in[8];
    const float* wo    = (const float*)d_in[9];
    const float* bo    = (const float*)d_in[10];
    float* out = (float*)d_out;

    // Workspace carve (~203 MB total; r8 proved ~206 MB works).
    char* p = (char*)d_ws;
    auto take = [&](size_t bytes) { char* r = p; p += (bytes + 255) & ~(size_t)255; return r; };
    float2* gpart = (float2*)take(1024 * 8);                   // 8 KB
    u16* wqb = (u16*)take((size_t)C_ * C_ * 2);
    u16* wkb = (u16*)take((size_t)C_ * C_ * 2);
    u16* wvb = (u16*)take((size_t)C_ * C_ * 2);
    u16* wob = (u16*)take((size_t)C_ * C_ * 2);
    u16* nx_t  = (u16*)take((size_t)B_ * N_ * C_ * 2);   // reused as attn_t
    u16* q_t   = (u16*)take((size_t)B_ * N_ * C_ * 2);
    u16* k_t   = (u16*)take((size_t)B_ * N_ * C_ * 2);
    u16* vbuf  = (u16*)take((size_t)B_ * C_ * N_ * 2);
    float* psum  = (float*)take((size_t)B_ * 32 * N_ * 4);     // 2 MB
    float* inv_l = (float*)take((size_t)B_ * N_ * 4);          // 64 KB
    u16* S_bf = (u16*)take((size_t)B_ * N_ * N_ * 2);          // 134 MB
    u16* attn_t = nx_t;    // nx_t is dead after qkv projections

    prep_kernel<<<1280, 256, 0, stream>>>(x, gpart, wq, wk, wv, wo,
                                          wqb, wkb, wvb, wob);
    nxt_kernel<<<dim3(N_ / 64, C_ / 64, B_), 256, 0, stream>>>(
        x, gpart, gamma, beta, nx_t);

    qkv_gemm<<<dim3(32, 4, 12), 256, 0, stream>>>(
        nx_t, wqb, wkb, wvb, bq, bk, bv, q_t, k_t, vbuf);

    scores_gemm<<<dim3(N_ / 128, N_ / 128, B_), 256, 0, stream>>>(q_t, k_t, S_bf, psum);
    lsum_kernel<<<B_ * N_ / 256, 256, 0, stream>>>(psum, inv_l);
    pv_part<<<1024, 256, 0, stream>>>(S_bf, vbuf, attn_t);

    final_gemm<<<dim3(N_ / 128, C_ / 128, B_), 256, 0, stream>>>(wob, attn_t, bo, x, inv_l, out);
}

// Round 20
// 259.584 us; speedup vs baseline: 1.0446x; 1.0446x over previous
//
#include <hip/hip_runtime.h>

// Problem constants (B=4, C=512, G=32, H=W=64)
#define B_   4
#define C_   512
#define G_   32
#define CPG  16          // channels per group
#define N_   4096        // H*W

typedef unsigned short u16;
typedef __attribute__((ext_vector_type(4))) float f32x4;
typedef __attribute__((ext_vector_type(8))) short s16x8;
typedef __attribute__((ext_vector_type(8))) u16   u16x8;
typedef __attribute__((ext_vector_type(4))) u16   u16x4;

__device__ __forceinline__ u16 f2bf(float f) {
    union { float f; unsigned u; } x; x.f = f;
    unsigned r = x.u + 0x7fffu + ((x.u >> 16) & 1u);   // RNE
    return (u16)(r >> 16);
}

// ---------------------------------------------------------------------------
// GroupNorm partial sums: 1024 blocks (8 per (b,g)), each reduces 8192 floats.
// ---------------------------------------------------------------------------
__global__ __launch_bounds__(256)
void gn_part_kernel(const float* __restrict__ x, float2* __restrict__ partial)
{
    int blk = blockIdx.x;            // 0..1023
    int bg = blk >> 3, s = blk & 7;  // group 0..127, slice 0..7
    const float* base = x + (size_t)bg * CPG * N_ + s * 8192;
    int t = threadIdx.x;

    float sm = 0.f, ss = 0.f;
    #pragma unroll
    for (int i = 0; i < 8192; i += 1024) {
        float4 v = *reinterpret_cast<const float4*>(base + i + t * 4);
        sm += v.x + v.y + v.z + v.w;
        ss += v.x * v.x + v.y * v.y + v.z * v.z + v.w * v.w;
    }
    __shared__ float rs[256], rss[256];
    rs[t] = sm; rss[t] = ss;
    __syncthreads();
    for (int off = 128; off > 0; off >>= 1) {
        if (t < off) { rs[t] += rs[t + off]; rss[t] += rss[t + off]; }
        __syncthreads();
    }
    if (t == 0) partial[blk] = make_float2(rs[0], rss[0]);
}

// Combine 8 partials per (b,g) in fixed order (deterministic), write
// per-channel scale/shift. One block, threads 0..127 = one (b,g) each.
__global__ __launch_bounds__(256)
void gn_combine_kernel(const float2* __restrict__ partial,
                       const float* __restrict__ gamma,
                       const float* __restrict__ beta,
                       float* __restrict__ scale, float* __restrict__ shift)
{
    int bg = threadIdx.x;
    if (bg >= 128) return;
    int b = bg >> 5, g = bg & 31;
    float sm = 0.f, ss = 0.f;
    #pragma unroll
    for (int s = 0; s < 8; ++s) {
        float2 p = partial[bg * 8 + s];
        sm += p.x; ss += p.y;
    }
    const float inv_n = 1.f / 65536.f;
    float mean = sm * inv_n;
    float var  = ss * inv_n - mean * mean;
    float rstd = rsqrtf(var + 1e-6f);
    #pragma unroll
    for (int cc = 0; cc < CPG; ++cc) {
        int c = g * CPG + cc;
        float sc = gamma[c] * rstd;
        scale[b * C_ + c] = sc;
        shift[b * C_ + c] = beta[c] - mean * sc;
    }
}

// ---------------------------------------------------------------------------
// Convert the four 512x512 weight matrices to bf16 (same [co][ci] layout).
// ---------------------------------------------------------------------------
__global__ __launch_bounds__(256)
void wcvt_kernel(const float* __restrict__ wq, const float* __restrict__ wk,
                 const float* __restrict__ wv, const float* __restrict__ wo,
                 u16* __restrict__ wqb, u16* __restrict__ wkb,
                 u16* __restrict__ wvb, u16* __restrict__ wob)
{
    int idx = (blockIdx.x * 256 + threadIdx.x) * 4;
    {
        float4 a = *reinterpret_cast<const float4*>(wq + idx);
        u16x4 r = { f2bf(a.x), f2bf(a.y), f2bf(a.z), f2bf(a.w) };
        *reinterpret_cast<u16x4*>(wqb + idx) = r;
    }
    {
        float4 a = *reinterpret_cast<const float4*>(wk + idx);
        u16x4 r = { f2bf(a.x), f2bf(a.y), f2bf(a.z), f2bf(a.w) };
        *reinterpret_cast<u16x4*>(wkb + idx) = r;
    }
    {
        float4 a = *reinterpret_cast<const float4*>(wv + idx);
        u16x4 r = { f2bf(a.x), f2bf(a.y), f2bf(a.z), f2bf(a.w) };
        *reinterpret_cast<u16x4*>(wvb + idx) = r;
    }
    {
        float4 a = *reinterpret_cast<const float4*>(wo + idx);
        u16x4 r = { f2bf(a.x), f2bf(a.y), f2bf(a.z), f2bf(a.w) };
        *reinterpret_cast<u16x4*>(wob + idx) = r;
    }
}

// ---------------------------------------------------------------------------
// GN-apply + transpose + bf16 convert: x[b][c][n] f32 -> nx_t[b][n][c] bf16.
// ---------------------------------------------------------------------------
__global__ __launch_bounds__(256)
void nxt_kernel(const float* __restrict__ x, const float* __restrict__ scale,
                const float* __restrict__ shift, u16* __restrict__ nx_t)
{
    int b  = blockIdx.z;
    int n0 = blockIdx.x * 64, c0 = blockIdx.y * 64;
    const float* xb = x + ((size_t)b * C_ + c0) * N_ + n0;
    u16* ob = nx_t + ((size_t)b * N_ + n0) * C_ + c0;
    int t = threadIdx.x;
    int tx = t & 15, ty = t >> 4;

    __shared__ float tile[64][65];
    #pragma unroll
    for (int r = 0; r < 4; ++r) {
        int c = ty * 4 + r;
        float sc = scale[b * C_ + c0 + c];
        float sh = shift[b * C_ + c0 + c];
        float4 v = *reinterpret_cast<const float4*>(xb + (size_t)c * N_ + tx * 4);
        tile[c][tx * 4 + 0] = v.x * sc + sh;
        tile[c][tx * 4 + 1] = v.y * sc + sh;
        tile[c][tx * 4 + 2] = v.z * sc + sh;
        tile[c][tx * 4 + 3] = v.w * sc + sh;
    }
    __syncthreads();
    int nn = t >> 2, cc0 = (t & 3) * 16;
    u16x8 o0, o1;
    #pragma unroll
    for (int j = 0; j < 8; ++j) o0[j] = f2bf(tile[cc0 + j][nn]);
    #pragma unroll
    for (int j = 0; j < 8; ++j) o1[j] = f2bf(tile[cc0 + 8 + j][nn]);
    *reinterpret_cast<u16x8*>(ob + (size_t)nn * C_ + cc0)     = o0;
    *reinterpret_cast<u16x8*>(ob + (size_t)nn * C_ + cc0 + 8) = o1;
}

// ---------------------------------------------------------------------------
// TN bf16 MFMA GEMM: D[i][j] = sum_k A[i][k] * B[j][k]
// BM x BN tile, BK=64, 4 waves (2x2), 16x16x32 MFMA, global_load_lds staging.
// Granule XOR-swizzle (both-sides, proven r5: bank conflicts = 0).
// EPI: 0 = bf16 out + bias[j]; 1 = bf16 out + bias[i];
//      2 = bf16 exp(acc*scl) out + BLOCK-REDUCED row sums -> psum;
//      3 = f32 out: acc * colsc[j] + bias[i] + resid[i][j]; 4 = bf16 plain.
// ---------------------------------------------------------------------------
template<int BM, int BN, int EPI>
__device__ __forceinline__
void gemm_dev(int i0, int j0,
              const u16* __restrict__ A, const u16* __restrict__ B,
              void* __restrict__ Dp, const float* __restrict__ bias,
              const float* __restrict__ resid,
              int Nn, int K, int lda, int ldb, float scl,
              float* __restrict__ psum, const float* __restrict__ colsc)
{
    constexpr int WM = BM / 2, WN = BN / 2;   // wave tile
    constexpr int MI = WM / 16, NI = WN / 16; // fragments per wave

    __shared__ u16 As[BM * 64];
    __shared__ u16 Bs[BN * 64];

    const int t  = threadIdx.x;
    const int l  = t & 63;
    const int w  = t >> 6;          // wave 0..3
    const int wr = w >> 1;          // i-half
    const int wc = w & 1;           // j-half

    const int srow = l >> 3;                    // row within 8-row segment
    const int sgr  = ((l & 7) ^ (l >> 3)) * 8;  // swizzled global k-offset (u16)

    const int fr = l & 15;          // fragment row
    const int q  = l >> 4;          // fragment k-quarter

    f32x4 acc[MI][NI];
    #pragma unroll
    for (int a = 0; a < MI; ++a)
        #pragma unroll
        for (int b2 = 0; b2 < NI; ++b2) acc[a][b2] = 0.f;

    for (int k0 = 0; k0 < K; k0 += 64) {
        #pragma unroll
        for (int r = 0; r < BM / 32; ++r) {
            int s = r * 4 + w;      // 8-row segment
            const u16* ga = A + (size_t)(i0 + s * 8 + srow) * lda + (k0 + sgr);
            __builtin_amdgcn_global_load_lds(
                (const __attribute__((address_space(1))) void*)ga,
                (__attribute__((address_space(3))) void*)&As[s * 512], 16, 0, 0);
        }
        #pragma unroll
        for (int r = 0; r < BN / 32; ++r) {
            int s = r * 4 + w;
            const u16* gb = B + (size_t)(j0 + s * 8 + srow) * ldb + (k0 + sgr);
            __builtin_amdgcn_global_load_lds(
                (const __attribute__((address_space(1))) void*)gb,
                (__attribute__((address_space(3))) void*)&Bs[s * 512], 16, 0, 0);
        }
        __syncthreads();

        #pragma unroll
        for (int h = 0; h < 2; ++h) {
            s16x8 af[MI], bfr[NI];
            #pragma unroll
            for (int mi = 0; mi < MI; ++mi) {
                int r = wr * WM + mi * 16 + fr;
                int p = (h * 4 + q) ^ (r & 7);
                af[mi] = *reinterpret_cast<const s16x8*>(&As[r * 64 + p * 8]);
            }
            #pragma unroll
            for (int ni = 0; ni < NI; ++ni) {
                int r = wc * WN + ni * 16 + fr;
                int p = (h * 4 + q) ^ (r & 7);
                bfr[ni] = *reinterpret_cast<const s16x8*>(&Bs[r * 64 + p * 8]);
            }
            #pragma unroll
            for (int mi = 0; mi < MI; ++mi)
                #pragma unroll
                for (int ni = 0; ni < NI; ++ni)
                    acc[mi][ni] = __builtin_amdgcn_mfma_f32_16x16x32_bf16(
                        af[mi], bfr[ni], acc[mi][ni], 0, 0, 0);
        }
        __syncthreads();
    }

    const int orow = (l >> 4) * 4;
    const int ocol = l & 15;

    if constexpr (EPI == 2) {
        __shared__ float sstl[2][2][64];   // [wr][wc][row64]
        u16* D = (u16*)Dp;
        #pragma unroll
        for (int mi = 0; mi < MI; ++mi) {
            int ib = i0 + wr * WM + mi * 16 + orow;
            float pr[4] = {0.f, 0.f, 0.f, 0.f};
            #pragma unroll
            for (int ni = 0; ni < NI; ++ni) {
                int jb = j0 + wc * WN + ni * 16 + ocol;
                #pragma unroll
                for (int e = 0; e < 4; ++e) {
                    float ex = __expf(acc[mi][ni][e] * scl);
                    D[(size_t)(ib + e) * Nn + jb] = f2bf(ex);
                    pr[e] += ex;
                }
            }
            #pragma unroll
            for (int e = 0; e < 4; ++e) {
                pr[e] += __shfl_xor(pr[e], 1);
                pr[e] += __shfl_xor(pr[e], 2);
                pr[e] += __shfl_xor(pr[e], 4);
                pr[e] += __shfl_xor(pr[e], 8);
            }
            if ((l & 15) == 0) {
                #pragma unroll
                for (int e = 0; e < 4; ++e)
                    sstl[wr][wc][mi * 16 + (l >> 4) * 4 + e] = pr[e];
            }
        }
        __syncthreads();
        if (t < 128) {
            int wr2 = t >> 6, r = t & 63;
            psum[i0 + wr2 * 64 + r] = sstl[wr2][0][r] + sstl[wr2][1][r];
        }
    } else {
        #pragma unroll
        for (int mi = 0; mi < MI; ++mi) {
            #pragma unroll
            for (int ni = 0; ni < NI; ++ni) {
                int ib = i0 + wr * WM + mi * 16 + orow;
                int jb = j0 + wc * WN + ni * 16 + ocol;
                if constexpr (EPI == 0 || EPI == 1 || EPI == 4) {
                    u16* D = (u16*)Dp;
                    float bj = 0.f;
                    if constexpr (EPI == 0) bj = bias[jb];
                    #pragma unroll
                    for (int e = 0; e < 4; ++e) {
                        float vv = acc[mi][ni][e];
                        if constexpr (EPI == 0) vv += bj;
                        if constexpr (EPI == 1) vv += bias[ib + e];
                        D[(size_t)(ib + e) * Nn + jb] = f2bf(vv);
                    }
                } else {   // EPI == 3: colsc per output column + bias + resid
                    float* D = (float*)Dp;
                    float cs = colsc[jb];
                    #pragma unroll
                    for (int e = 0; e < 4; ++e)
                        D[(size_t)(ib + e) * Nn + jb] =
                            acc[mi][ni][e] * cs + bias[ib + e] + resid[(size_t)(ib + e) * Nn + jb];
                }
            }
        }
    }
}

// q_t/k_t: D[n][co] = sum_ci nx_t[n][ci] * W[co][ci] + b[co].  grid (4,32,8)
__global__ __launch_bounds__(256)
void qk_gemm(const u16* __restrict__ nx_t, const u16* __restrict__ wqb,
             const u16* __restrict__ wkb, const float* __restrict__ bq,
             const float* __restrict__ bk, u16* __restrict__ q_t,
             u16* __restrict__ k_t)
{
    int z = blockIdx.z, b = z & 3, isk = z >> 2;
    gemm_dev<128, 128, 0>(blockIdx.y * 128, blockIdx.x * 128,
                          nx_t + (size_t)b * N_ * C_, isk ? wkb : wqb,
                          (isk ? k_t : q_t) + (size_t)b * N_ * C_,
                          isk ? bk : bq, nullptr, C_, C_, C_, C_, 1.f,
                          nullptr, nullptr);
}

// v: D[co][n] = sum_ci Wv[co][ci] * nx_t[n][ci] + bv[co].  grid (32,4,4)
__global__ __launch_bounds__(256)
void v_gemm(const u16* __restrict__ wvb, const u16* __restrict__ nx_t,
            const float* __restrict__ bv, u16* __restrict__ vbuf)
{
    int b = blockIdx.z;
    gemm_dev<128, 128, 1>(blockIdx.y * 128, blockIdx.x * 128,
                          wvb, nx_t + (size_t)b * N_ * C_, vbuf + (size_t)b * C_ * N_,
                          bv, nullptr, N_, C_, C_, C_, 1.f, nullptr, nullptr);
}

// scores: P_raw[b][i][j] = exp(S) bf16 + block-reduced row-sum partials.
// r13-proven 3-D grid (32,32,4).
__global__ __launch_bounds__(256)
void scores_gemm(const u16* __restrict__ q_t, const u16* __restrict__ k_t,
                 u16* __restrict__ S_bf, float* __restrict__ psum)
{
    int b = blockIdx.z;
    float* ps = psum + ((size_t)b * 32 + blockIdx.x) * N_;   // [b][jt][i]
    gemm_dev<128, 128, 2>(blockIdx.y * 128, blockIdx.x * 128,
                          q_t + (size_t)b * N_ * C_, k_t + (size_t)b * N_ * C_,
                          S_bf + (size_t)b * N_ * N_, nullptr, nullptr, N_, C_, C_, C_,
                          0.044194173824159216f, ps, nullptr);
}

// Combine psum[b][jt][i] over jt -> inv_l[b*N+i]. 2 MB, L2-resident.
// grid B*N/256 x 256.
__global__ __launch_bounds__(256)
void lsum_kernel(const float* __restrict__ psum, float* __restrict__ inv_l)
{
    int r = blockIdx.x * 256 + threadIdx.x;   // global row b*N+i
    int b = r >> 12, i = r & (N_ - 1);
    const float* p = psum + (size_t)b * 32 * N_ + i;
    float s = 0.f;
    #pragma unroll
    for (int jt = 0; jt < 32; ++jt) s += p[(size_t)jt * N_];
    inv_l[r] = 1.f / s;
}

// ---------------------------------------------------------------------------
// PV (unnormalized): attn_t[i][c] = sum_j P_raw[i][j] * v[c][j].
// r13-proven plain body. LDS staging, XOR swizzle, XCD-gather, BM=128 i,
// BN=64 c, BK=64. grid 1024 blocks.
// ---------------------------------------------------------------------------
__global__ __launch_bounds__(256)
void pv_part(const u16* __restrict__ S_bf, const u16* __restrict__ vbuf,
             u16* __restrict__ attn_t)
{
    int id  = blockIdx.x;          // 0..1023
    int xcd = id & 7, slot = id >> 3;
    int yz  = xcd * 16 + (slot >> 3);   // (i-tile, b) combo, 0..127
    int ct  = slot & 7;                 // c-tile 0..7
    int it  = yz & 31, b = yz >> 5;
    const u16* Pb = S_bf + (size_t)b * N_ * N_;
    const u16* Vb = vbuf + (size_t)b * C_ * N_;
    u16*       Ob = attn_t + (size_t)b * N_ * C_;

    const int i0 = it * 128, c0 = ct * 64;
    const int t = threadIdx.x, l = t & 63, w = t >> 6;
    const int wr = w >> 1, wc = w & 1;       // WM=64, WN=32, MI=4, NI=2
    const int srow = l >> 3;
    const int sgr  = ((l & 7) ^ (l >> 3)) * 8;
    const int fr = l & 15, q = l >> 4;

    __shared__ u16 As[128 * 64];
    __shared__ u16 Bs[64 * 64];

    f32x4 acc[4][2];
    #pragma unroll
    for (int a = 0; a < 4; ++a)
        #pragma unroll
        for (int b2 = 0; b2 < 2; ++b2) acc[a][b2] = 0.f;

    for (int k0 = 0; k0 < N_; k0 += 64) {
        #pragma unroll
        for (int r = 0; r < 4; ++r) {
            int s = r * 4 + w;
            const u16* ga = Pb + (size_t)(i0 + s * 8 + srow) * N_ + (k0 + sgr);
            __builtin_amdgcn_global_load_lds(
                (const __attribute__((address_space(1))) void*)ga,
                (__attribute__((address_space(3))) void*)&As[s * 512], 16, 0, 0);
        }
        #pragma unroll
        for (int r = 0; r < 2; ++r) {
            int s = r * 4 + w;
            const u16* gb = Vb + (size_t)(c0 + s * 8 + srow) * N_ + (k0 + sgr);
            __builtin_amdgcn_global_load_lds(
                (const __attribute__((address_space(1))) void*)gb,
                (__attribute__((address_space(3))) void*)&Bs[s * 512], 16, 0, 0);
        }
        __syncthreads();
        #pragma unroll
        for (int h = 0; h < 2; ++h) {
            s16x8 af[4], bfr[2];
            #pragma unroll
            for (int mi = 0; mi < 4; ++mi) {
                int r = wr * 64 + mi * 16 + fr;
                int p = (h * 4 + q) ^ (r & 7);
                af[mi] = *reinterpret_cast<const s16x8*>(&As[r * 64 + p * 8]);
            }
            #pragma unroll
            for (int ni = 0; ni < 2; ++ni) {
                int r = wc * 32 + ni * 16 + fr;
                int p = (h * 4 + q) ^ (r & 7);
                bfr[ni] = *reinterpret_cast<const s16x8*>(&Bs[r * 64 + p * 8]);
            }
            #pragma unroll
            for (int mi = 0; mi < 4; ++mi)
                #pragma unroll
                for (int ni = 0; ni < 2; ++ni)
                    acc[mi][ni] = __builtin_amdgcn_mfma_f32_16x16x32_bf16(
                        af[mi], bfr[ni], acc[mi][ni], 0, 0, 0);
        }
        __syncthreads();
    }

    const int orow = (l >> 4) * 4;
    const int ocol = l & 15;
    #pragma unroll
    for (int mi = 0; mi < 4; ++mi) {
        #pragma unroll
        for (int ni = 0; ni < 2; ++ni) {
            int ib = i0 + wr * 64 + mi * 16 + orow;
            int jb = c0 + wc * 32 + ni * 16 + ocol;
            #pragma unroll
            for (int e = 0; e < 4; ++e)
                Ob[(size_t)(ib + e) * C_ + jb] = f2bf(acc[mi][ni][e]);
        }
    }
}

// final: out[co][n] = x + bo[co] + inv_l[n] * sum_ci wo[co][ci]*attn_t[n][ci].
// grid (32,4,4)
__global__ __launch_bounds__(256)
void final_gemm(const u16* __restrict__ wob, const u16* __restrict__ attn_t,
                const float* __restrict__ bo, const float* __restrict__ x,
                const float* __restrict__ inv_l, float* __restrict__ outp)
{
    int b = blockIdx.z;
    gemm_dev<128, 128, 3>(blockIdx.y * 128, blockIdx.x * 128,
                          wob, attn_t + (size_t)b * N_ * C_, outp + (size_t)b * C_ * N_,
                          bo, x + (size_t)b * C_ * N_, N_, C_, C_, C_, 1.f,
                          nullptr, inv_l + (size_t)b * N_);
}

// ---------------------------------------------------------------------------
extern "C" void kernel_launch(void* const* d_in, const int* in_sizes, int n_in,
                              void* d_out, int out_size, void* d_ws, size_t ws_size,
                              hipStream_t stream)
{
    const float* x     = (const float*)d_in[0];
    const float* gamma = (const float*)d_in[1];
    const float* beta  = (const float*)d_in[2];
    const float* wq    = (const float*)d_in[3];
    const float* bq    = (const float*)d_in[4];
    const float* wk    = (const float*)d_in[5];
    const float* bk    = (const float*)d_in[6];
    const float* wv    = (const float*)d_in[7];
    const float* bv    = (const float*)d_in[8];
    const float* wo    = (const float*)d_in[9];
    const float* bo    = (const float*)d_in[10];
    float* out = (float*)d_out;

    // Workspace carve (~203 MB total; r8 proved ~206 MB works).
    char* p = (char*)d_ws;
    auto take = [&](size_t bytes) { char* r = p; p += (bytes + 255) & ~(size_t)255; return r; };
    float* scale = (float*)take(B_ * C_ * 4);
    float* shift = (float*)take(B_ * C_ * 4);
    float2* gpart = (float2*)take(1024 * 8);                   // 8 KB
    u16* wqb = (u16*)take((size_t)C_ * C_ * 2);
    u16* wkb = (u16*)take((size_t)C_ * C_ * 2);
    u16* wvb = (u16*)take((size_t)C_ * C_ * 2);
    u16* wob = (u16*)take((size_t)C_ * C_ * 2);
    u16* nx_t  = (u16*)take((size_t)B_ * N_ * C_ * 2);   // reused as attn_t
    u16* q_t   = (u16*)take((size_t)B_ * N_ * C_ * 2);
    u16* k_t   = (u16*)take((size_t)B_ * N_ * C_ * 2);
    u16* vbuf  = (u16*)take((size_t)B_ * C_ * N_ * 2);
    float* psum  = (float*)take((size_t)B_ * 32 * N_ * 4);     // 2 MB
    float* inv_l = (float*)take((size_t)B_ * N_ * 4);          // 64 KB
    u16* S_bf = (u16*)take((size_t)B_ * N_ * N_ * 2);          // 134 MB
    u16* attn_t = nx_t;    // nx_t is dead after qkv projections

    gn_part_kernel<<<1024, 256, 0, stream>>>(x, gpart);
    gn_combine_kernel<<<1, 256, 0, stream>>>(gpart, gamma, beta, scale, shift);
    wcvt_kernel<<<256, 256, 0, stream>>>(wq, wk, wv, wo, wqb, wkb, wvb, wob);
    nxt_kernel<<<dim3(N_ / 64, C_ / 64, B_), 256, 0, stream>>>(x, scale, shift, nx_t);

    qk_gemm<<<dim3(C_ / 128, N_ / 128, 8), 256, 0, stream>>>(nx_t, wqb, wkb, bq, bk, q_t, k_t);
    v_gemm<<<dim3(N_ / 128, C_ / 128, B_), 256, 0, stream>>>(wvb, nx_t, bv, vbuf);

    scores_gemm<<<dim3(N_ / 128, N_ / 128, B_), 256, 0, stream>>>(q_t, k_t, S_bf, psum);
    lsum_kernel<<<B_ * N_ / 256, 256, 0, stream>>>(psum, inv_l);
    pv_part<<<1024, 256, 0, stream>>>(S_bf, vbuf, attn_t);

    final_gemm<<<dim3(N_ / 128, C_ / 128, B_), 256, 0, stream>>>(wob, attn_t, bo, x, inv_l, out);
}